// Round 16
// baseline (435.762 us; speedup 1.0000x reference)
//
#include <hip/hip_runtime.h>
#include <hip/hip_bf16.h>
#include <math.h>
#include <stdint.h>

// ---------------- types & helpers ----------------
typedef __attribute__((ext_vector_type(8))) short short8;   // 8 x bf16 (MFMA A/B frag)
typedef __attribute__((ext_vector_type(4))) float floatx4;  // MFMA C/D frag

#define DEVI __device__ __forceinline__

DEVI float b2f(unsigned short u) {
    union { unsigned int i; float f; } v; v.i = ((unsigned int)u) << 16; return v.f;
}
DEVI unsigned short f2b(float f) {   // RNE f32 -> bf16
    unsigned int x = __float_as_uint(f);
    unsigned int r = (x + 0x7fffu + ((x >> 16) & 1u)) >> 16;
    return (unsigned short)r;
}

// global -> LDS direct (16B per lane). LDS dest must be wave-uniform base + lane*16.
#define GLD16(gp, lp)                                                            \
    __builtin_amdgcn_global_load_lds(                                            \
        (__attribute__((address_space(1))) unsigned int*)(gp),                   \
        (__attribute__((address_space(3))) unsigned int*)(lp), 16, 0, 0)

static constexpr int NQ = 4096, NS = 16384;
static constexpr int NROW_Q = 4 * NQ;   // 16384 query rows
static constexpr int NROW_S = 4 * NS;   // 65536 source rows
static constexpr float INV2PI = 0.15915494309189535f;

// h-buffer (activation) LDS layout for fused chains: short index =
// nf*1280 + row*20 + i  (nf = col>>4, i = col&15, row block-local 0..63).
// Row stride 20 (not 16): write banks lg*40%32={0,8,16,24} + l15/2 -> 2-way (free);
// read banks 10*l15 mod 32 all-distinct -> 2-way (free). Frag read (lane lg,l15, kt):
// byte = ((kt*2+(lg>>1))*1280 + (wave*16+l15)*20 + (lg&1)*8)*2, 16B contiguous.

// ---------------- prep: weight conversions, penc0, bp2 ----------------
// z=0: Wproj -> transposed [n][128k]; z=6: caWo -> transposed [n][256k]
// z=3/4/5/7/8: Wq/Wk/Wv/W1/W2 -> FRAGMENT-MAJOR (r15-verified): frag for (tile,kt)
// at ((tile*8+kt)*64 + lg*16 + (n&15))*8 + j, holding out-col n, k = kt*32+lg*8+j.
__global__ void k_prep(const float* Wproj, const float* caWq, const float* caWk,
                       const float* caWv, const float* caWo, const float* W1,
                       const float* W2, const float* b_pos,
                       unsigned short* wTproj, unsigned short* wTcaWqf,
                       unsigned short* wTkv, unsigned short* wTcaWo,
                       unsigned short* wTW1f, unsigned short* wTW2f,
                       float* penc0, float* bp2)
{
    int z = blockIdx.z;
    if (z == 9) {   // penc0[c] = pos_enc(0): [0,0,0, cos(b_pos)]; bp2 = b_pos/2pi
        if (blockIdx.x == 0 && blockIdx.y == 0) {
            int c = threadIdx.y * 16 + threadIdx.x;
            float v = 0.f;
            if (c >= 3) {
                float rev = b_pos[c - 3] * INV2PI;
                bp2[c - 3] = rev;
                rev -= floorf(rev);
                v = __builtin_amdgcn_cosf(rev);
            }
            penc0[c] = v;
        }
        return;
    }
    if (z == 1 || z == 2) return;            // saWv/saWo handled by k_wfuse
    int n = blockIdx.x * 16 + threadIdx.x;   // output col of the weight
    int k = blockIdx.y * 16 + threadIdx.y;   // input (k) index
    if (z == 0) { if (k < 128) wTproj[(size_t)n * 128 + k] = f2b(Wproj[(size_t)k * 256 + n]); return; }
    if (z == 6) { wTcaWo[(size_t)n * 256 + k] = f2b(caWo[(size_t)k * 256 + n]); return; }
    const float* src; unsigned short* dst; int tadd = 0;
    if (z == 3)      { src = caWq; dst = wTcaWqf; }
    else if (z == 4) { src = caWk; dst = wTkv; }
    else if (z == 5) { src = caWv; dst = wTkv; tadd = 16; }
    else if (z == 7) { src = W1;   dst = wTW1f; }
    else             { src = W2;   dst = wTW2f; }
    int tile = tadd + (n >> 4);
    int kt = k >> 5, lgi = (k >> 3) & 3, j = k & 7;
    dst[(size_t)((tile * 8 + kt) * 64 + lgi * 16 + (n & 15)) * 8 + j] =
        f2b(src[(size_t)k * 256 + n]);
}

// fuse self-attn (linear-linear): Wsa = saWv @ saWo -> FRAGMENT-MAJOR; bsa = bv@Wo + bo
__global__ void k_wfuse(const float* Wv, const float* Wo, const float* bv, const float* bo,
                        unsigned short* wsaf, float* bsa)
{
    int k = blockIdx.x, n = threadIdx.x;
    float s = 0.f;
    for (int c = 0; c < 256; ++c) s = fmaf(Wv[k * 256 + c], Wo[c * 256 + n], s);
    int tile = n >> 4, kt = k >> 5, lgi = (k >> 3) & 3, j = k & 7;
    wsaf[(size_t)((tile * 8 + kt) * 64 + lgi * 16 + (n & 15)) * 8 + j] = f2b(s);
    if (k == 0) {
        float s2 = bo[n];
        for (int c = 0; c < 256; ++c) s2 = fmaf(bv[c], Wo[c * 256 + n], s2);
        bsa[n] = s2;
    }
}

// ---------------- f32 -> bf16 convert ----------------
__global__ void k_cvt(const float* in, unsigned short* out, int n4)
{
    int i = blockIdx.x * blockDim.x + threadIdx.x;
    int stride = gridDim.x * blockDim.x;
    for (; i < n4; i += stride) {
        float4 v = ((const float4*)in)[i];
        unsigned long long p =
              (unsigned long long)f2b(v.x)
            | ((unsigned long long)f2b(v.y) << 16)
            | ((unsigned long long)f2b(v.z) << 32)
            | ((unsigned long long)f2b(v.w) << 48);
        ((unsigned long long*)out)[i] = p;
    }
}

// ---------------- MFMA GEMM (bf16 out, +bias) for the src projection ----------------
template<int EPI>
__global__ __launch_bounds__(256, 2)
void k_gemm(const unsigned short* A, const unsigned short* BT, const float* bias,
            const float* extra, void* outp, int M, int N, int K)
{
    __shared__ alignas(16) unsigned short lA[128 * 64];  // [128 rows][64 k], swizzled
    __shared__ alignas(16) unsigned short lB[64 * 64];   // [64 rows][64 k], swizzled
    const int tid = threadIdx.x;
    const int wave = tid >> 6, lane = tid & 63;
    const int m0 = blockIdx.x * 128, n0 = blockIdx.y * 64;
    const int wm = (wave >> 1) * 64, wn = (wave & 1) * 32;
    floatx4 acc[4][2] = {};

    for (int kt = 0; kt < K; kt += 64) {
        __syncthreads();
        #pragma unroll
        for (int c = 0; c < 4; ++c) {   // stage A tile 16KB
            int o = (tid + c * 256) * 16;
            int row = o >> 7, inner = o & 127;
            int srk = inner ^ ((row & 7) << 4);
            GLD16((const char*)A + ((size_t)(m0 + row) * K + kt) * 2 + srk, (char*)lA + o);
        }
        #pragma unroll
        for (int c = 0; c < 2; ++c) {   // stage B tile 8KB
            int o = (tid + c * 256) * 16;
            int row = o >> 7, inner = o & 127;
            int srk = inner ^ ((row & 7) << 4);
            GLD16((const char*)BT + ((size_t)(n0 + row) * K + kt) * 2 + srk, (char*)lB + o);
        }
        __syncthreads();
        #pragma unroll
        for (int kc = 0; kc < 2; ++kc) {
            const int kb = kc * 64 + ((lane >> 4) << 4);
            short8 bf[2];
            #pragma unroll
            for (int nf = 0; nf < 2; ++nf) {
                int nn = wn + nf * 16 + (lane & 15);
                bf[nf] = *(const short8*)((const char*)lB + nn * 128 + (kb ^ ((nn & 7) << 4)));
            }
            #pragma unroll
            for (int mf = 0; mf < 4; ++mf) {
                int rr = wm + mf * 16 + (lane & 15);
                short8 af = *(const short8*)((const char*)lA + rr * 128 + (kb ^ ((rr & 7) << 4)));
                acc[mf][0] = __builtin_amdgcn_mfma_f32_16x16x32_bf16(af, bf[0], acc[mf][0], 0, 0, 0);
                acc[mf][1] = __builtin_amdgcn_mfma_f32_16x16x32_bf16(af, bf[1], acc[mf][1], 0, 0, 0);
            }
        }
    }
    #pragma unroll
    for (int mf = 0; mf < 4; ++mf)
        #pragma unroll
        for (int nf = 0; nf < 2; ++nf)
            #pragma unroll
            for (int r = 0; r < 4; ++r) {
                int row = m0 + wm + mf * 16 + ((lane >> 4) << 2) + r;
                int col = n0 + wn + nf * 16 + (lane & 15);
                float v = acc[mf][nf][r] + bias[col];
                ((unsigned short*)outp)[(size_t)row * N + col] = f2b(v);
            }
    (void)extra;
}

// ---------------- LN stats helper (in-wave row reduce over l15 group) ----------------
#define LNSTATS(A, MEAN, INV)                                                     \
    do {                                                                          \
        _Pragma("unroll")                                                         \
        for (int r = 0; r < 4; ++r) {                                             \
            float s_ = 0.f;                                                       \
            _Pragma("unroll")                                                     \
            for (int nf = 0; nf < 16; ++nf) s_ += A[nf][r];                       \
            _Pragma("unroll")                                                     \
            for (int t = 1; t <= 8; t <<= 1) s_ += __shfl_xor(s_, t);             \
            MEAN[r] = s_ * (1.f / 256.f);                                         \
            float q_ = 0.f;                                                       \
            _Pragma("unroll")                                                     \
            for (int nf = 0; nf < 16; ++nf) {                                     \
                float d_ = A[nf][r] - MEAN[r]; q_ += d_ * d_;                     \
            }                                                                     \
            _Pragma("unroll")                                                     \
            for (int t = 1; t <= 8; t <<= 1) q_ += __shfl_xor(q_, t);             \
            INV[r] = 1.0f / sqrtf(q_ * (1.f / 256.f) + 1e-5f);                    \
        }                                                                         \
    } while (0)

// ---------------- fused query chain: proj+penc -> LN1 -> @Wsa(+qx) -> LN2 -> @Wq ------
// 64 rows/block, 256 thr. Wave w owns rows w*16..w*16+15 for all passes.
// Pass1 staged GEMM (K=128); passes 2-3: A from padded LDS h-buffer, B fragment-major.
__global__ __launch_bounds__(256, 2)
void k_qchain(const unsigned short* A, const unsigned short* BT,
              const float* bproj, const float* penc0,
              const float* ln1g, const float* ln1b,
              const unsigned short* wsaf, const float* bsa,
              const float* ln2g, const float* ln2b,
              const unsigned short* wqf, const float* bq,
              float* xbuf, unsigned short* qbuf)
{
    __shared__ alignas(16) unsigned short lA[64 * 64];       // 8 KB
    __shared__ alignas(16) unsigned short hB[16 * 64 * 20];  // 40 KB; [0,32K) = staging
    const int tid = threadIdx.x, wave = tid >> 6, lane = tid & 63;
    const int l15 = lane & 15, lg = lane >> 4;
    const int m0 = blockIdx.x * 64;
    const int hrow = wave * 16;

    floatx4 aq[16] = {};
    // ---- pass1: qfb @ WprojT (K=128) ----
    for (int kt0 = 0; kt0 < 128; kt0 += 64) {
        __syncthreads();
        #pragma unroll
        for (int c = 0; c < 2; ++c) {
            int o = (tid + c * 256) * 16;
            int row = o >> 7, inner = o & 127;
            int srk = inner ^ ((row & 7) << 4);
            GLD16((const char*)A + ((size_t)(m0 + row) * 128 + kt0) * 2 + srk, (char*)lA + o);
        }
        #pragma unroll
        for (int c = 0; c < 8; ++c) {
            int o = (tid + c * 256) * 16;
            int row = o >> 7, inner = o & 127;
            int srk = inner ^ ((row & 7) << 4);
            GLD16((const char*)BT + ((size_t)row * 128 + kt0) * 2 + srk, (char*)hB + o);
        }
        __syncthreads();
        #pragma unroll
        for (int kc = 0; kc < 2; ++kc) {
            const int kb = kc * 64 + (lg << 4);
            int rr = hrow + l15;
            short8 af = *(const short8*)((const char*)lA + rr * 128 + (kb ^ ((rr & 7) << 4)));
            #pragma unroll
            for (int nf = 0; nf < 16; ++nf) {
                int nn = nf * 16 + l15;
                short8 bf = *(const short8*)((const char*)hB + nn * 128 + (kb ^ ((nn & 7) << 4)));
                aq[nf] = __builtin_amdgcn_mfma_f32_16x16x32_bf16(af, bf, aq[nf], 0, 0, 0);
            }
        }
    }
    // epilogue1: qx = aq + bproj + penc0 (stays in regs)
    #pragma unroll
    for (int nf = 0; nf < 16; ++nf) {
        float bi = bproj[nf * 16 + l15] + penc0[nf * 16 + l15];
        #pragma unroll
        for (int r = 0; r < 4; ++r) aq[nf][r] += bi;
    }
    float mean[4], inv[4];
    LNSTATS(aq, mean, inv);
    __syncthreads();   // pass1 staging reads complete
    #pragma unroll
    for (int nf = 0; nf < 16; ++nf) {
        int col = nf * 16 + l15;
        float g = ln1g[col], b = ln1b[col];
        #pragma unroll
        for (int r = 0; r < 4; ++r)
            hB[nf * 1280 + (hrow + lg * 4 + r) * 20 + l15] =
                f2b((aq[nf][r] - mean[r]) * inv[r] * g + b);
    }
    __syncthreads();
    // ---- pass2: xv = LN1 @ Wsa + bsa + qx ----
    floatx4 as[16] = {};
    #pragma unroll
    for (int kt = 0; kt < 8; ++kt) {
        short8 af = *(const short8*)((const char*)hB +
                     ((kt * 2 + (lg >> 1)) * 1280 + (hrow + l15) * 20 + (lg & 1) * 8) * 2);
        #pragma unroll
        for (int nf = 0; nf < 16; ++nf) {
            short8 bf = *(const short8*)((const char*)wsaf + ((size_t)((nf * 8 + kt) * 64 + lane) << 4));
            as[nf] = __builtin_amdgcn_mfma_f32_16x16x32_bf16(af, bf, as[nf], 0, 0, 0);
        }
    }
    #pragma unroll
    for (int nf = 0; nf < 16; ++nf) {
        int col = nf * 16 + l15;
        float bi = bsa[col];
        #pragma unroll
        for (int r = 0; r < 4; ++r) {
            float v = as[nf][r] + bi + aq[nf][r];
            as[nf][r] = v;
            xbuf[(size_t)(m0 + hrow + lg * 4 + r) * 256 + col] = v;
        }
    }
    LNSTATS(as, mean, inv);
    __syncthreads();   // pass2 h reads complete
    #pragma unroll
    for (int nf = 0; nf < 16; ++nf) {
        int col = nf * 16 + l15;
        float g = ln2g[col], b = ln2b[col];
        #pragma unroll
        for (int r = 0; r < 4; ++r)
            hB[nf * 1280 + (hrow + lg * 4 + r) * 20 + l15] =
                f2b((as[nf][r] - mean[r]) * inv[r] * g + b);
    }
    __syncthreads();
    // ---- pass3: qbuf = LN2 @ Wq + bq (reuse aq regs; qx dead) ----
    #pragma unroll
    for (int nf = 0; nf < 16; ++nf) aq[nf] = floatx4{0.f, 0.f, 0.f, 0.f};
    #pragma unroll
    for (int kt = 0; kt < 8; ++kt) {
        short8 af = *(const short8*)((const char*)hB +
                     ((kt * 2 + (lg >> 1)) * 1280 + (hrow + l15) * 20 + (lg & 1) * 8) * 2);
        #pragma unroll
        for (int nf = 0; nf < 16; ++nf) {
            short8 bf = *(const short8*)((const char*)wqf + ((size_t)((nf * 8 + kt) * 64 + lane) << 4));
            aq[nf] = __builtin_amdgcn_mfma_f32_16x16x32_bf16(af, bf, aq[nf], 0, 0, 0);
        }
    }
    #pragma unroll
    for (int nf = 0; nf < 16; ++nf) {
        int col = nf * 16 + l15;
        float bi = bq[col];
        #pragma unroll
        for (int r = 0; r < 4; ++r)
            qbuf[(size_t)(m0 + hrow + lg * 4 + r) * 256 + col] = f2b(aq[nf][r] + bi);
    }
}

// ---------------- fused tail: ctx@Wo+bo+xbuf -> LN3 -> @W1+relu -> @W2 (+x2, nan) ----
__global__ __launch_bounds__(256, 2)
void k_tail(const unsigned short* ctx, const unsigned short* BT,
            const float* bo, const float* xbuf,
            const float* ln3g, const float* ln3b,
            const unsigned short* w1f, const float* b1,
            const unsigned short* w2f, const float* b2, float* out)
{
    __shared__ alignas(16) unsigned short lA[64 * 64];       // 8 KB
    __shared__ alignas(16) unsigned short hB[16 * 64 * 20];  // 40 KB; [0,32K) = staging
    const int tid = threadIdx.x, wave = tid >> 6, lane = tid & 63;
    const int l15 = lane & 15, lg = lane >> 4;
    const int m0 = blockIdx.x * 64;
    const int hrow = wave * 16;

    floatx4 ax[16] = {};
    // ---- pass1: ctx @ WcaO^T (K=256) ----
    for (int kt0 = 0; kt0 < 256; kt0 += 64) {
        __syncthreads();
        #pragma unroll
        for (int c = 0; c < 2; ++c) {
            int o = (tid + c * 256) * 16;
            int row = o >> 7, inner = o & 127;
            int srk = inner ^ ((row & 7) << 4);
            GLD16((const char*)ctx + ((size_t)(m0 + row) * 256 + kt0) * 2 + srk, (char*)lA + o);
        }
        #pragma unroll
        for (int c = 0; c < 8; ++c) {
            int o = (tid + c * 256) * 16;
            int row = o >> 7, inner = o & 127;
            int srk = inner ^ ((row & 7) << 4);
            GLD16((const char*)BT + ((size_t)row * 256 + kt0) * 2 + srk, (char*)hB + o);
        }
        __syncthreads();
        #pragma unroll
        for (int kc = 0; kc < 2; ++kc) {
            const int kb = kc * 64 + (lg << 4);
            int rr = hrow + l15;
            short8 af = *(const short8*)((const char*)lA + rr * 128 + (kb ^ ((rr & 7) << 4)));
            #pragma unroll
            for (int nf = 0; nf < 16; ++nf) {
                int nn = nf * 16 + l15;
                short8 bf = *(const short8*)((const char*)hB + nn * 128 + (kb ^ ((nn & 7) << 4)));
                ax[nf] = __builtin_amdgcn_mfma_f32_16x16x32_bf16(af, bf, ax[nf], 0, 0, 0);
            }
        }
    }
    // epilogue1: x2 = ax + bo + xbuf (stays in regs)
    #pragma unroll
    for (int nf = 0; nf < 16; ++nf) {
        int col = nf * 16 + l15;
        float bi = bo[col];
        #pragma unroll
        for (int r = 0; r < 4; ++r)
            ax[nf][r] += bi + xbuf[(size_t)(m0 + hrow + lg * 4 + r) * 256 + col];
    }
    float mean[4], inv[4];
    LNSTATS(ax, mean, inv);
    __syncthreads();
    #pragma unroll
    for (int nf = 0; nf < 16; ++nf) {
        int col = nf * 16 + l15;
        float g = ln3g[col], b = ln3b[col];
        #pragma unroll
        for (int r = 0; r < 4; ++r)
            hB[nf * 1280 + (hrow + lg * 4 + r) * 20 + l15] =
                f2b((ax[nf][r] - mean[r]) * inv[r] * g + b);
    }
    __syncthreads();
    // ---- pass2: h1 = relu(LN3 @ W1 + b1) ----
    floatx4 a1[16] = {};
    #pragma unroll
    for (int kt = 0; kt < 8; ++kt) {
        short8 af = *(const short8*)((const char*)hB +
                     ((kt * 2 + (lg >> 1)) * 1280 + (hrow + l15) * 20 + (lg & 1) * 8) * 2);
        #pragma unroll
        for (int nf = 0; nf < 16; ++nf) {
            short8 bf = *(const short8*)((const char*)w1f + ((size_t)((nf * 8 + kt) * 64 + lane) << 4));
            a1[nf] = __builtin_amdgcn_mfma_f32_16x16x32_bf16(af, bf, a1[nf], 0, 0, 0);
        }
    }
    __syncthreads();   // pass2 h reads complete
    #pragma unroll
    for (int nf = 0; nf < 16; ++nf) {
        float bi = b1[nf * 16 + l15];
        #pragma unroll
        for (int r = 0; r < 4; ++r)
            hB[nf * 1280 + (hrow + lg * 4 + r) * 20 + l15] = f2b(fmaxf(a1[nf][r] + bi, 0.f));
    }
    __syncthreads();
    // ---- pass3: out = h1 @ W2 + b2 + x2, nan_to_num (reuse a1) ----
    #pragma unroll
    for (int nf = 0; nf < 16; ++nf) a1[nf] = floatx4{0.f, 0.f, 0.f, 0.f};
    #pragma unroll
    for (int kt = 0; kt < 8; ++kt) {
        short8 af = *(const short8*)((const char*)hB +
                     ((kt * 2 + (lg >> 1)) * 1280 + (hrow + l15) * 20 + (lg & 1) * 8) * 2);
        #pragma unroll
        for (int nf = 0; nf < 16; ++nf) {
            short8 bf = *(const short8*)((const char*)w2f + ((size_t)((nf * 8 + kt) * 64 + lane) << 4));
            a1[nf] = __builtin_amdgcn_mfma_f32_16x16x32_bf16(af, bf, a1[nf], 0, 0, 0);
        }
    }
    #pragma unroll
    for (int nf = 0; nf < 16; ++nf) {
        int col = nf * 16 + l15;
        float bi = b2[col];
        #pragma unroll
        for (int r = 0; r < 4; ++r) {
            float v = a1[nf][r] + bi + ax[nf][r];
            if (isnan(v)) v = 0.f;
            else if (isinf(v)) v = v > 0.f ? 3.402823466e38f : -3.402823466e38f;
            out[(size_t)(m0 + hrow + lg * 4 + r) * 256 + col] = v;
        }
    }
}

// ---------------- fused neighbor attention (r15: fragment-major weights, 4 blocks/CU) ----
__global__ __launch_bounds__(256, 4)
void k_attn(const unsigned short* srcp, const unsigned short* qb, const int* inds,
            const float* s_pts, const float* q_pts, const float* W_pos, const float* bp2,
            const unsigned short* wTkv, const float* bv, unsigned short* ctx)
{
    __shared__ alignas(16) unsigned short nx[64 * 256];   // 32 KB, XOR-swizzled rows
    __shared__ alignas(16) float att_lds[4 * 16 * 16];    // 4 KB [q][h][k]
    __shared__ alignas(16) unsigned short qls[4 * 256];   // 2 KB raw q (bf16)
    __shared__ alignas(16) float dist_lds[64];            // (dist/RADIUS)^2
    const int tid = threadIdx.x, wave = tid >> 6, lane = tid & 63;
    const int qbase = blockIdx.x * 4;
    const int l15 = lane & 15, lg = lane >> 4;

    if (tid < 128)
        *(uint4*)&qls[tid * 8] = *(const uint4*)(qb + (size_t)qbase * 256 + tid * 8);

    float bvv[4];
    #pragma unroll
    for (int nf = 0; nf < 4; ++nf) bvv[nf] = bv[(wave * 4 + nf) * 16 + l15];

    // ---- P1: gather + positional encoding ----
    {
        int r = tid >> 2, sub = tid & 3;
        int qi = qbase + (r >> 4);
        int bb = qi >> 12;
        int k = r & 15;
        int raw = inds[((size_t)qi << 4) + k];
        int idx = raw % (NS + 1); if (idx < 0) idx += NS + 1;
        bool shadow = (idx == NS);
        const int c0 = sub * 64;
        const unsigned short* srow = srcp + ((size_t)bb * NS + (shadow ? 0 : idx)) * 256 + c0;
        short8 sv[8];
        #pragma unroll
        for (int j = 0; j < 8; ++j) sv[j] = *(const short8*)(srow + j * 8);

        float px = q_pts[(size_t)qi * 3], py = q_pts[(size_t)qi * 3 + 1], pz = q_pts[(size_t)qi * 3 + 2];
        float sx, sy, sz;
        if (shadow) { sx = sy = sz = 1e6f; }
        else {
            const float* sp = s_pts + ((size_t)bb * NS + idx) * 3;
            sx = sp[0]; sy = sp[1]; sz = sp[2];
        }
        float tx = (sx - px) * 0.25f, ty = (sy - py) * 0.25f, tz = (sz - pz) * 0.25f;
        if (sub == 0) dist_lds[r] = tx * tx + ty * ty + tz * tz;

        #pragma unroll
        for (int cc = 0; cc < 64; cc += 8) {
            short8 vals;
            #pragma unroll
            for (int j = 0; j < 8; ++j) {
                int c = c0 + cc + j;
                float pe;
                if (c == 0) pe = tx;
                else if (c == 1) pe = ty;
                else if (c == 2) pe = tz;
                else {
                    int jj = c - 3;
                    float rev = fmaf(tx, W_pos[jj],
                                fmaf(ty, W_pos[253 + jj],
                                fmaf(tz, W_pos[506 + jj], bp2[jj])));
                    rev -= floorf(rev);
                    pe = __builtin_amdgcn_cosf(rev);
                }
                float sval = shadow ? 0.f : b2f((unsigned short)sv[cc / 8][j]);
                vals[j] = (short)f2b(sval + pe);
            }
            int byte = (c0 + cc) * 2;
            *(short8*)((char*)nx + r * 512 + (byte ^ ((r & 7) << 4))) = vals;
        }
    }
    __syncthreads();

    floatx4 acc[4][4];

    // ---- P2: kk = nx @ Wk ----
    #pragma unroll
    for (int mf = 0; mf < 4; ++mf)
        #pragma unroll
        for (int nf = 0; nf < 4; ++nf) acc[mf][nf] = floatx4{0.f, 0.f, 0.f, 0.f};

    #pragma unroll 2
    for (int kt = 0; kt < 8; ++kt) {
        const int kb = kt * 64 + (lg << 4);
        short8 bfr[4];
        #pragma unroll
        for (int nf = 0; nf < 4; ++nf) {
            int tile = wave * 4 + nf;
            bfr[nf] = *(const short8*)((const char*)wTkv + (size_t)(((tile * 8 + kt) * 64 + lane) << 4));
        }
        #pragma unroll
        for (int mf = 0; mf < 4; ++mf) {
            int rr = mf * 16 + l15;
            short8 af = *(const short8*)((const char*)nx + rr * 512 + (kb ^ ((rr & 7) << 4)));
            #pragma unroll
            for (int nf = 0; nf < 4; ++nf)
                acc[mf][nf] = __builtin_amdgcn_mfma_f32_16x16x32_bf16(af, bfr[nf], acc[mf][nf], 0, 0, 0);
        }
    }

    // ---- P3: scores + softmax ----
    {
        #pragma unroll
        for (int mf = 0; mf < 4; ++mf) {
            float4 d4 = *(const float4*)&dist_lds[mf * 16 + lg * 4];
            float dd4[4] = {d4.x, d4.y, d4.z, d4.w};
            #pragma unroll
            for (int nf = 0; nf < 4; ++nf) {
                float qvv = b2f(qls[mf * 256 + (wave * 4 + nf) * 16 + l15]);
                float s[4];
                #pragma unroll
                for (int rr = 0; rr < 4; ++rr) s[rr] = acc[mf][nf][rr] * qvv;
                #pragma unroll
                for (int t = 1; t <= 8; t <<= 1)
                    #pragma unroll
                    for (int rr = 0; rr < 4; ++rr) s[rr] += __shfl_xor(s[rr], t);
                #pragma unroll
                for (int rr = 0; rr < 4; ++rr)
                    s[rr] = (dd4[rr] > 1.0f) ? -1e9f : s[rr] * 0.25f;
                float m = fmaxf(fmaxf(s[0], s[1]), fmaxf(s[2], s[3]));
                m = fmaxf(m, __shfl_xor(m, 16));
                m = fmaxf(m, __shfl_xor(m, 32));
                float p[4], su = 0.f;
                #pragma unroll
                for (int rr = 0; rr < 4; ++rr) { p[rr] = __expf(s[rr] - m); su += p[rr]; }
                su += __shfl_xor(su, 16);
                su += __shfl_xor(su, 32);
                float iv = __builtin_amdgcn_rcpf(su);
                if (l15 == 0) {
                    float4 a4 = {p[0] * iv, p[1] * iv, p[2] * iv, p[3] * iv};
                    *(float4*)&att_lds[(mf * 16 + wave * 4 + nf) * 16 + lg * 4] = a4;
                }
            }
        }
    }

    // ---- P4: vv = nx @ Wv, ctx = att . vv ----
    #pragma unroll
    for (int mf = 0; mf < 4; ++mf)
        #pragma unroll
        for (int nf = 0; nf < 4; ++nf) acc[mf][nf] = floatx4{0.f, 0.f, 0.f, 0.f};

    #pragma unroll 2
    for (int kt = 0; kt < 8; ++kt) {
        const int kb = kt * 64 + (lg << 4);
        short8 bfr[4];
        #pragma unroll
        for (int nf = 0; nf < 4; ++nf) {
            int tile = 16 + wave * 4 + nf;
            bfr[nf] = *(const short8*)((const char*)wTkv + (size_t)(((tile * 8 + kt) * 64 + lane) << 4));
        }
        #pragma unroll
        for (int mf = 0; mf < 4; ++mf) {
            int rr = mf * 16 + l15;
            short8 af = *(const short8*)((const char*)nx + rr * 512 + (kb ^ ((rr & 7) << 4)));
            #pragma unroll
            for (int nf = 0; nf < 4; ++nf)
                acc[mf][nf] = __builtin_amdgcn_mfma_f32_16x16x32_bf16(af, bfr[nf], acc[mf][nf], 0, 0, 0);
        }
    }

    {
        #pragma unroll
        for (int mf = 0; mf < 4; ++mf)
            #pragma unroll
            for (int nf = 0; nf < 4; ++nf) {
                float4 a4 = *(const float4*)&att_lds[(mf * 16 + wave * 4 + nf) * 16 + lg * 4];
                float o = a4.x * acc[mf][nf][0];
                o = fmaf(a4.y, acc[mf][nf][1], o);
                o = fmaf(a4.z, acc[mf][nf][2], o);
                o = fmaf(a4.w, acc[mf][nf][3], o);
                o += __shfl_xor(o, 16);
                o += __shfl_xor(o, 32);
                o += bvv[nf];
                if (lane < 16)
                    ctx[(size_t)(qbase + mf) * 256 + (wave * 4 + nf) * 16 + lane] = f2b(o);
            }
    }
}

// ---------------- host launcher ----------------
extern "C" void kernel_launch(void* const* d_in, const int* in_sizes, int n_in,
                              void* d_out, int out_size, void* d_ws, size_t ws_size,
                              hipStream_t stream)
{
    const float* q_pts   = (const float*)d_in[0];
    const float* s_pts   = (const float*)d_in[1];
    const float* src_f   = (const float*)d_in[2];
    const float* query_f = (const float*)d_in[3];
    const float* W_proj  = (const float*)d_in[4];
    const float* b_proj  = (const float*)d_in[5];
    const float* W_pos   = (const float*)d_in[6];
    const float* b_pos   = (const float*)d_in[7];
    const float* ln1_g   = (const float*)d_in[8];
    const float* ln1_b   = (const float*)d_in[9];
    const float* sa_Wv   = (const float*)d_in[10];
    const float* sa_bv   = (const float*)d_in[11];
    const float* sa_Wo   = (const float*)d_in[12];
    const float* sa_bo   = (const float*)d_in[13];
    const float* ln2_g   = (const float*)d_in[14];
    const float* ln2_b   = (const float*)d_in[15];
    const float* ca_Wq   = (const float*)d_in[16];
    const float* ca_bq   = (const float*)d_in[17];
    const float* ca_Wk   = (const float*)d_in[18];
    /* ca_bk = d_in[19] unused: softmax shift-invariant */
    const float* ca_Wv   = (const float*)d_in[20];
    const float* ca_bv   = (const float*)d_in[21];
    const float* ca_Wo   = (const float*)d_in[22];
    const float* ca_bo   = (const float*)d_in[23];
    const float* ln3_g   = (const float*)d_in[24];
    const float* ln3_b   = (const float*)d_in[25];
    const float* W1      = (const float*)d_in[26];
    const float* b1      = (const float*)d_in[27];
    const float* W2      = (const float*)d_in[28];
    const float* b2      = (const float*)d_in[29];
    const int*   inds    = (const int*)d_in[30];

    char* ws = (char*)d_ws;
    size_t off = 0;
    auto alloc = [&](size_t bytes) { char* p = ws + off; off += (bytes + 1023) & ~(size_t)1023; return p; };

    unsigned short* wTproj  = (unsigned short*)alloc(256 * 128 * 2);
    unsigned short* wTcaWqf = (unsigned short*)alloc(256 * 256 * 2);
    unsigned short* wTkv    = (unsigned short*)alloc(512 * 256 * 2);
    unsigned short* wTcaWo  = (unsigned short*)alloc(256 * 256 * 2);
    unsigned short* wTW1f   = (unsigned short*)alloc(256 * 256 * 2);
    unsigned short* wTW2f   = (unsigned short*)alloc(256 * 256 * 2);
    unsigned short* wsaf    = (unsigned short*)alloc(256 * 256 * 2);
    float*          bsa     = (float*)alloc(256 * 4);
    float*          penc0   = (float*)alloc(256 * 4);
    float*          bp2     = (float*)alloc(256 * 4);
    unsigned short* srcb    = (unsigned short*)alloc((size_t)NROW_S * 128 * 2);
    unsigned short* qfb     = (unsigned short*)alloc((size_t)NROW_Q * 128 * 2);
    unsigned short* srcp    = (unsigned short*)alloc((size_t)NROW_S * 256 * 2);
    float*          xbuf    = (float*)alloc((size_t)NROW_Q * 256 * 4);
    unsigned short* qbuf    = (unsigned short*)alloc((size_t)NROW_Q * 256 * 2);
    unsigned short* ctxbuf  = (unsigned short*)alloc((size_t)NROW_Q * 256 * 2);

    dim3 bl16(16, 16);
    k_prep<<<dim3(16, 16, 10), bl16, 0, stream>>>(
        W_proj, ca_Wq, ca_Wk, ca_Wv, ca_Wo, W1, W2, b_pos,
        wTproj, wTcaWqf, wTkv, wTcaWo, wTW1f, wTW2f, penc0, bp2);
    k_wfuse<<<256, 256, 0, stream>>>(sa_Wv, sa_Wo, sa_bv, sa_bo, wsaf, bsa);

    k_cvt<<<1024, 256, 0, stream>>>(src_f, srcb, NROW_S * 128 / 4);
    k_cvt<<<1024, 256, 0, stream>>>(query_f, qfb, NROW_Q * 128 / 4);

    // src_p = src @ W_proj + b_proj  (bf16)
    k_gemm<0><<<dim3(512, 4), 256, 0, stream>>>(srcb, wTproj, b_proj, nullptr, srcp, NROW_S, 256, 128);

    // fused query chain: xbuf (f32) + qbuf (bf16)
    k_qchain<<<256, 256, 0, stream>>>(qfb, wTproj, b_proj, penc0, ln1_g, ln1_b,
                                      wsaf, bsa, ln2_g, ln2_b, wTcaWqf, ca_bq, xbuf, qbuf);

    // cross-attention
    k_attn<<<4096, 256, 0, stream>>>(srcp, qbuf, inds, s_pts, q_pts, W_pos, bp2, wTkv, ca_bv, ctxbuf);

    // fused tail: ctx@Wo + residual -> LN3 -> FFN -> d_out (f32, nan_to_num)
    k_tail<<<256, 256, 0, stream>>>(ctxbuf, wTcaWo, ca_bo, xbuf, ln3_g, ln3_b,
                                    wTW1f, b1, wTW2f, b2, (float*)d_out);

    (void)in_sizes; (void)n_in; (void)out_size; (void)ws_size;
}

// Round 17
// 420.193 us; speedup vs baseline: 1.0371x; 1.0371x over previous
//
#include <hip/hip_runtime.h>
#include <hip/hip_bf16.h>
#include <math.h>
#include <stdint.h>

// ---------------- types & helpers ----------------
typedef __attribute__((ext_vector_type(8))) short short8;   // 8 x bf16 (MFMA A/B frag)
typedef __attribute__((ext_vector_type(4))) float floatx4;  // MFMA C/D frag

#define DEVI __device__ __forceinline__

DEVI float b2f(unsigned short u) {
    union { unsigned int i; float f; } v; v.i = ((unsigned int)u) << 16; return v.f;
}
DEVI unsigned short f2b(float f) {   // RNE f32 -> bf16
    unsigned int x = __float_as_uint(f);
    unsigned int r = (x + 0x7fffu + ((x >> 16) & 1u)) >> 16;
    return (unsigned short)r;
}

// global -> LDS direct (16B per lane). LDS dest must be wave-uniform base + lane*16.
#define GLD16(gp, lp)                                                            \
    __builtin_amdgcn_global_load_lds(                                            \
        (__attribute__((address_space(1))) unsigned int*)(gp),                   \
        (__attribute__((address_space(3))) unsigned int*)(lp), 16, 0, 0)

static constexpr int NQ = 4096, NS = 16384;
static constexpr int NROW_Q = 4 * NQ;   // 16384 query rows
static constexpr int NROW_S = 4 * NS;   // 65536 source rows
static constexpr float INV2PI = 0.15915494309189535f;

// ---------------- prep: transpose weights to bf16 [N][K], penc0, bp2 ----------------
// wTkv uses the FRAGMENT-MAJOR layout (r15-verified): frag for (tile, kt) at
// ((tile*8 + kt)*64 + lane)*16B -> weight loads in k_attn fully coalesced.
__global__ void k_prep(const float* Wproj, const float* saWv, const float* saWo,
                       const float* caWq, const float* caWk, const float* caWv,
                       const float* caWo, const float* W1, const float* W2,
                       const float* b_pos,
                       unsigned short* wTproj, unsigned short* wTcaWq,
                       unsigned short* wTkv, unsigned short* wTcaWo,
                       unsigned short* wTW1, unsigned short* wTW2, float* penc0, float* bp2)
{
    int z = blockIdx.z;
    if (z == 9) {   // penc0[c] = pos_enc(0): [0,0,0, cos(b_pos)]; bp2 = b_pos/2pi
        if (blockIdx.x == 0 && blockIdx.y == 0) {
            int c = threadIdx.y * 16 + threadIdx.x;
            float v = 0.f;
            if (c >= 3) {
                float rev = b_pos[c - 3] * INV2PI;
                bp2[c - 3] = rev;
                rev -= floorf(rev);
                v = __builtin_amdgcn_cosf(rev);
            }
            penc0[c] = v;
        }
        return;
    }
    if (z == 1 || z == 2) return;            // saWv/saWo handled by k_wfuse
    int n = blockIdx.x * 16 + threadIdx.x;   // output row (orig col)
    int k = blockIdx.y * 16 + threadIdx.y;   // output col (orig row)
    if (z == 4 || z == 5) {                  // caWk / caWv -> fragment-major wTkv
        int tile = (z == 5 ? 16 : 0) + (n >> 4);
        int kt = k >> 5, lg = (k >> 3) & 3, j = k & 7;
        int lane = lg * 16 + (n & 15);
        wTkv[(size_t)(((tile * 8 + kt) * 64 + lane) * 8 + j)] =
            f2b((z == 4 ? caWk : caWv)[(size_t)k * 256 + n]);
        return;
    }
    const float* src; unsigned short* dst; int K = 256;
    switch (z) {
        case 0: src = Wproj; dst = wTproj; K = 128; break;
        case 3: src = caWq;  dst = wTcaWq; break;
        case 6: src = caWo;  dst = wTcaWo; break;
        case 7: src = W1;    dst = wTW1;   break;
        default: src = W2;   dst = wTW2;   break;
    }
    if (k < K) dst[(size_t)n * K + k] = f2b(src[(size_t)k * 256 + n]);
    (void)saWv; (void)saWo;
}

// fuse self-attn (linear-linear): Wsa = saWv @ saWo (bf16 [n][k]), bsa = bv@Wo + bo
// k = blockIdx (Wv row, scalar-broadcast loads), n = threadIdx (coalesced Wo reads)
__global__ void k_wfuse(const float* Wv, const float* Wo, const float* bv, const float* bo,
                        unsigned short* wTsa, float* bsa)
{
    int k = blockIdx.x, n = threadIdx.x;
    float s = 0.f;
    for (int c = 0; c < 256; ++c) s = fmaf(Wv[k * 256 + c], Wo[c * 256 + n], s);
    wTsa[n * 256 + k] = f2b(s);
    if (k == 0) {
        float s2 = bo[n];
        for (int c = 0; c < 256; ++c) s2 = fmaf(bv[c], Wo[c * 256 + n], s2);
        bsa[n] = s2;
    }
}

// ---------------- f32 -> bf16 convert ----------------
__global__ void k_cvt(const float* in, unsigned short* out, int n4)
{
    int i = blockIdx.x * blockDim.x + threadIdx.x;
    int stride = gridDim.x * blockDim.x;
    for (; i < n4; i += stride) {
        float4 v = ((const float4*)in)[i];
        unsigned long long p =
              (unsigned long long)f2b(v.x)
            | ((unsigned long long)f2b(v.y) << 16)
            | ((unsigned long long)f2b(v.z) << 32)
            | ((unsigned long long)f2b(v.w) << 48);
        ((unsigned long long*)out)[i] = p;
    }
}

// ---------------- MFMA GEMM: out[M][N] = A[M][K](bf16) @ BT[N][K]^T + epilogue ----------------
// EPI: 0 = bf16 out, +bias   1 = bf16 out, +bias, relu   4 = f32 out, +bias+extra, nan_to_num
template<int EPI>
__global__ __launch_bounds__(256, 2)
void k_gemm(const unsigned short* A, const unsigned short* BT, const float* bias,
            const float* extra, void* outp, int M, int N, int K)
{
    __shared__ alignas(16) unsigned short lA[128 * 64];  // [128 rows][64 k], swizzled
    __shared__ alignas(16) unsigned short lB[64 * 64];   // [64 rows][64 k], swizzled
    const int tid = threadIdx.x;
    const int wave = tid >> 6, lane = tid & 63;
    const int m0 = blockIdx.x * 128, n0 = blockIdx.y * 64;
    const int wm = (wave >> 1) * 64, wn = (wave & 1) * 32;
    floatx4 acc[4][2] = {};

    for (int kt = 0; kt < K; kt += 64) {
        __syncthreads();
        #pragma unroll
        for (int c = 0; c < 4; ++c) {   // stage A tile 16KB
            int o = (tid + c * 256) * 16;
            int row = o >> 7, inner = o & 127;
            int srk = inner ^ ((row & 7) << 4);
            GLD16((const char*)A + ((size_t)(m0 + row) * K + kt) * 2 + srk, (char*)lA + o);
        }
        #pragma unroll
        for (int c = 0; c < 2; ++c) {   // stage B tile 8KB
            int o = (tid + c * 256) * 16;
            int row = o >> 7, inner = o & 127;
            int srk = inner ^ ((row & 7) << 4);
            GLD16((const char*)BT + ((size_t)(n0 + row) * K + kt) * 2 + srk, (char*)lB + o);
        }
        __syncthreads();
        #pragma unroll
        for (int kc = 0; kc < 2; ++kc) {
            const int kb = kc * 64 + ((lane >> 4) << 4);
            short8 bf[2];
            #pragma unroll
            for (int nf = 0; nf < 2; ++nf) {
                int nn = wn + nf * 16 + (lane & 15);
                bf[nf] = *(const short8*)((const char*)lB + nn * 128 + (kb ^ ((nn & 7) << 4)));
            }
            #pragma unroll
            for (int mf = 0; mf < 4; ++mf) {
                int rr = wm + mf * 16 + (lane & 15);
                short8 af = *(const short8*)((const char*)lA + rr * 128 + (kb ^ ((rr & 7) << 4)));
                acc[mf][0] = __builtin_amdgcn_mfma_f32_16x16x32_bf16(af, bf[0], acc[mf][0], 0, 0, 0);
                acc[mf][1] = __builtin_amdgcn_mfma_f32_16x16x32_bf16(af, bf[1], acc[mf][1], 0, 0, 0);
            }
        }
    }
    #pragma unroll
    for (int mf = 0; mf < 4; ++mf)
        #pragma unroll
        for (int nf = 0; nf < 2; ++nf)
            #pragma unroll
            for (int r = 0; r < 4; ++r) {
                int row = m0 + wm + mf * 16 + ((lane >> 4) << 2) + r;
                int col = n0 + wn + nf * 16 + (lane & 15);
                float v = acc[mf][nf][r] + bias[col];
                if (EPI == 4) v += extra[(size_t)row * N + col];
                if (EPI == 1) v = fmaxf(v, 0.f);
                if (EPI == 4) {
                    if (isnan(v)) v = 0.f;
                    else if (isinf(v)) v = v > 0.f ? 3.402823466e38f : -3.402823466e38f;
                }
                if (EPI == 0 || EPI == 1)
                    ((unsigned short*)outp)[(size_t)row * N + col] = f2b(v);
                else
                    ((float*)outp)[(size_t)row * N + col] = v;
            }
}

// ---------------- fused GEMM + row-LayerNorm epilogue (r15-proven) ----------------
template<int EPI2>
__global__ __launch_bounds__(256, 2)
void k_gemm_ln(const unsigned short* A, const unsigned short* BT, const float* bias,
               const float* extra, const float* lng, const float* lnb,
               float* outf, unsigned short* outb, int M, int K)
{
    __shared__ alignas(16) unsigned short lA[64 * 64];    // 8 KB
    __shared__ alignas(16) unsigned short lB[256 * 64];   // 32 KB
    const int tid = threadIdx.x, wave = tid >> 6, lane = tid & 63;
    const int l15 = lane & 15, lg = lane >> 4;
    const int m0 = blockIdx.x * 64;
    floatx4 acc[16] = {};

    for (int kt = 0; kt < K; kt += 64) {
        __syncthreads();
        #pragma unroll
        for (int c = 0; c < 2; ++c) {   // stage A 8KB
            int o = (tid + c * 256) * 16;
            int row = o >> 7, inner = o & 127;
            int srk = inner ^ ((row & 7) << 4);
            GLD16((const char*)A + ((size_t)(m0 + row) * K + kt) * 2 + srk, (char*)lA + o);
        }
        #pragma unroll
        for (int c = 0; c < 8; ++c) {   // stage B 32KB (all 256 n-rows)
            int o = (tid + c * 256) * 16;
            int row = o >> 7, inner = o & 127;
            int srk = inner ^ ((row & 7) << 4);
            GLD16((const char*)BT + ((size_t)row * K + kt) * 2 + srk, (char*)lB + o);
        }
        __syncthreads();
        #pragma unroll
        for (int kc = 0; kc < 2; ++kc) {
            const int kb = kc * 64 + (lg << 4);
            int rr = wave * 16 + l15;
            short8 af = *(const short8*)((const char*)lA + rr * 128 + (kb ^ ((rr & 7) << 4)));
            #pragma unroll
            for (int nf = 0; nf < 16; ++nf) {
                int nn = nf * 16 + l15;
                short8 bf = *(const short8*)((const char*)lB + nn * 128 + (kb ^ ((nn & 7) << 4)));
                acc[nf] = __builtin_amdgcn_mfma_f32_16x16x32_bf16(af, bf, acc[nf], 0, 0, 0);
            }
        }
    }

    #pragma unroll
    for (int nf = 0; nf < 16; ++nf) {
        int col = nf * 16 + l15;
        float bi = bias[col] + (EPI2 == 0 ? extra[col] : 0.f);
        #pragma unroll
        for (int r = 0; r < 4; ++r) {
            int row = m0 + wave * 16 + lg * 4 + r;
            float v = acc[nf][r] + bi;
            if (EPI2 == 1) v += extra[(size_t)row * 256 + col];
            acc[nf][r] = v;
            outf[(size_t)row * 256 + col] = v;
        }
    }
    float mean[4], inv[4];
    #pragma unroll
    for (int r = 0; r < 4; ++r) {
        float s = 0.f;
        #pragma unroll
        for (int nf = 0; nf < 16; ++nf) s += acc[nf][r];
        #pragma unroll
        for (int t = 1; t <= 8; t <<= 1) s += __shfl_xor(s, t);
        mean[r] = s * (1.f / 256.f);
        float q = 0.f;
        #pragma unroll
        for (int nf = 0; nf < 16; ++nf) { float d = acc[nf][r] - mean[r]; q += d * d; }
        #pragma unroll
        for (int t = 1; t <= 8; t <<= 1) q += __shfl_xor(q, t);
        inv[r] = 1.0f / sqrtf(q * (1.f / 256.f) + 1e-5f);
    }
    #pragma unroll
    for (int nf = 0; nf < 16; ++nf) {
        int col = nf * 16 + l15;
        float g = lng[col], b = lnb[col];
        #pragma unroll
        for (int r = 0; r < 4; ++r) {
            int row = m0 + wave * 16 + lg * 4 + r;
            outb[(size_t)row * 256 + col] = f2b((acc[nf][r] - mean[r]) * inv[r] * g + b);
        }
    }
}

// ---------------- fused neighbor attention (r15 + coalesced row-contiguous gather) ------
// block = 4 queries (64 rows), 256 thr, 4 blocks/CU. Weights fragment-major (r15).
// NEW gather: leaders (tid&3==0) compute t/dist/idx -> LDS; barrier; then 32 consecutive
// lanes read one srcp row contiguously (2 rows/wave/load -> 8 cache lines vs 64).
__global__ __launch_bounds__(256, 4)
void k_attn(const unsigned short* srcp, const unsigned short* qb, const int* inds,
            const float* s_pts, const float* q_pts, const float* W_pos, const float* bp2,
            const unsigned short* wTkv, const float* bv, unsigned short* ctx)
{
    __shared__ alignas(16) unsigned short nx[64 * 256];   // 32 KB, XOR-swizzled rows
    __shared__ alignas(16) float att_lds[4 * 16 * 16];    // 4 KB [q][h][k]
    __shared__ alignas(16) unsigned short qls[4 * 256];   // 2 KB raw q (bf16)
    __shared__ alignas(16) float4 t_lds[64];              // 1 KB {tx,ty,tz,-}
    __shared__ alignas(16) float dist_lds[64];            // 256 B
    __shared__ alignas(16) int idx_lds[64];               // 256 B (-1 = shadow)
    const int tid = threadIdx.x, wave = tid >> 6, lane = tid & 63;
    const int qbase = blockIdx.x * 4;
    const int l15 = lane & 15, lg = lane >> 4;
    const int l31 = lane & 31, lh5 = lane >> 5;

    // ---- stage raw q into LDS (coalesced; 128 threads x 16B = 2KB) ----
    if (tid < 128)
        *(uint4*)&qls[tid * 8] = *(const uint4*)(qb + (size_t)qbase * 256 + tid * 8);

    float bvv[4];
    #pragma unroll
    for (int nf = 0; nf < 4; ++nf) bvv[nf] = bv[(wave * 4 + nf) * 16 + l15];

    // ---- Phase A: per-row leaders compute t-vec / dist / idx ----
    if ((tid & 3) == 0) {
        int row = tid >> 2;
        int qi = qbase + (row >> 4);
        int bb = qi >> 12;
        int raw = inds[((size_t)qi << 4) + (row & 15)];
        int idx = raw % (NS + 1); if (idx < 0) idx += NS + 1;
        bool shadow = (idx == NS);
        float px = q_pts[(size_t)qi * 3], py = q_pts[(size_t)qi * 3 + 1], pz = q_pts[(size_t)qi * 3 + 2];
        float sx, sy, sz;
        if (shadow) { sx = sy = sz = 1e6f; }
        else { const float* sp = s_pts + ((size_t)bb * NS + idx) * 3; sx = sp[0]; sy = sp[1]; sz = sp[2]; }
        float tx = (sx - px) * 0.25f, ty = (sy - py) * 0.25f, tz = (sz - pz) * 0.25f;
        t_lds[row] = make_float4(tx, ty, tz, 0.f);
        dist_lds[row] = tx * tx + ty * ty + tz * tz;   // shadow -> huge -> masked
        idx_lds[row] = shadow ? -1 : idx;
    }
    __syncthreads();

    // ---- Phase B: coalesced gather (all 8 loads issued before any cook) ----
    {
        short8 sv[8];
        #pragma unroll
        for (int g8 = 0; g8 < 8; ++g8) {
            int row = wave * 16 + g8 * 2 + lh5;
            int qi = qbase + (row >> 4);
            int bb = qi >> 12;
            int idxv = idx_lds[row];
            int srow = idxv < 0 ? 0 : idxv;
            sv[g8] = *(const short8*)(srcp + ((size_t)bb * NS + srow) * 256 + l31 * 8);
        }
        #pragma unroll
        for (int g8 = 0; g8 < 8; ++g8) {
            int row = wave * 16 + g8 * 2 + lh5;
            float4 t4 = t_lds[row];
            bool sh = (idx_lds[row] < 0);
            const int c0g = l31 * 8;
            short8 vals;
            #pragma unroll
            for (int j = 0; j < 8; ++j) {
                int c = c0g + j;
                float pe;
                if (c == 0) pe = t4.x;
                else if (c == 1) pe = t4.y;
                else if (c == 2) pe = t4.z;
                else {
                    int jj = c - 3;
                    float rev = fmaf(t4.x, W_pos[jj],
                                fmaf(t4.y, W_pos[253 + jj],
                                fmaf(t4.z, W_pos[506 + jj], bp2[jj])));
                    rev -= floorf(rev);
                    pe = __builtin_amdgcn_cosf(rev);
                }
                float sval = sh ? 0.f : b2f((unsigned short)sv[g8][j]);
                vals[j] = (short)f2b(sval + pe);
            }
            *(short8*)((char*)nx + row * 512 + ((c0g * 2) ^ ((row & 7) << 4))) = vals;
        }
    }
    __syncthreads();

    floatx4 acc[4][4];

    // ---- P2: kk = nx @ Wk (fragment-major weights) ----
    #pragma unroll
    for (int mf = 0; mf < 4; ++mf)
        #pragma unroll
        for (int nf = 0; nf < 4; ++nf) acc[mf][nf] = floatx4{0.f, 0.f, 0.f, 0.f};

    #pragma unroll 2
    for (int kt = 0; kt < 8; ++kt) {
        const int kb = kt * 64 + (lg << 4);
        short8 bfr[4];
        #pragma unroll
        for (int nf = 0; nf < 4; ++nf) {
            int tile = wave * 4 + nf;
            bfr[nf] = *(const short8*)((const char*)wTkv + (size_t)(((tile * 8 + kt) * 64 + lane) << 4));
        }
        #pragma unroll
        for (int mf = 0; mf < 4; ++mf) {
            int rr = mf * 16 + l15;
            short8 af = *(const short8*)((const char*)nx + rr * 512 + (kb ^ ((rr & 7) << 4)));
            #pragma unroll
            for (int nf = 0; nf < 4; ++nf)
                acc[mf][nf] = __builtin_amdgcn_mfma_f32_16x16x32_bf16(af, bfr[nf], acc[mf][nf], 0, 0, 0);
        }
    }

    // ---- P3: scores + softmax (in-register; qv from LDS) ----
    {
        #pragma unroll
        for (int mf = 0; mf < 4; ++mf) {
            float4 d4 = *(const float4*)&dist_lds[mf * 16 + lg * 4];
            float dd4[4] = {d4.x, d4.y, d4.z, d4.w};
            #pragma unroll
            for (int nf = 0; nf < 4; ++nf) {
                float qvv = b2f(qls[mf * 256 + (wave * 4 + nf) * 16 + l15]);
                float s[4];
                #pragma unroll
                for (int rr = 0; rr < 4; ++rr) s[rr] = acc[mf][nf][rr] * qvv;
                #pragma unroll
                for (int t = 1; t <= 8; t <<= 1)
                    #pragma unroll
                    for (int rr = 0; rr < 4; ++rr) s[rr] += __shfl_xor(s[rr], t);
                #pragma unroll
                for (int rr = 0; rr < 4; ++rr)
                    s[rr] = (dd4[rr] > 1.0f) ? -1e9f : s[rr] * 0.25f;
                float m = fmaxf(fmaxf(s[0], s[1]), fmaxf(s[2], s[3]));
                m = fmaxf(m, __shfl_xor(m, 16));
                m = fmaxf(m, __shfl_xor(m, 32));
                float p[4], su = 0.f;
                #pragma unroll
                for (int rr = 0; rr < 4; ++rr) { p[rr] = __expf(s[rr] - m); su += p[rr]; }
                su += __shfl_xor(su, 16);
                su += __shfl_xor(su, 32);
                float iv = __builtin_amdgcn_rcpf(su);
                if (l15 == 0) {
                    float4 a4 = {p[0] * iv, p[1] * iv, p[2] * iv, p[3] * iv};
                    *(float4*)&att_lds[(mf * 16 + wave * 4 + nf) * 16 + lg * 4] = a4;
                }
            }
        }
    }

    // ---- P4: vv = nx @ Wv, ctx = att . vv ----
    #pragma unroll
    for (int mf = 0; mf < 4; ++mf)
        #pragma unroll
        for (int nf = 0; nf < 4; ++nf) acc[mf][nf] = floatx4{0.f, 0.f, 0.f, 0.f};

    #pragma unroll 2
    for (int kt = 0; kt < 8; ++kt) {
        const int kb = kt * 64 + (lg << 4);
        short8 bfr[4];
        #pragma unroll
        for (int nf = 0; nf < 4; ++nf) {
            int tile = 16 + wave * 4 + nf;
            bfr[nf] = *(const short8*)((const char*)wTkv + (size_t)(((tile * 8 + kt) * 64 + lane) << 4));
        }
        #pragma unroll
        for (int mf = 0; mf < 4; ++mf) {
            int rr = mf * 16 + l15;
            short8 af = *(const short8*)((const char*)nx + rr * 512 + (kb ^ ((rr & 7) << 4)));
            #pragma unroll
            for (int nf = 0; nf < 4; ++nf)
                acc[mf][nf] = __builtin_amdgcn_mfma_f32_16x16x32_bf16(af, bfr[nf], acc[mf][nf], 0, 0, 0);
        }
    }

    {
        #pragma unroll
        for (int mf = 0; mf < 4; ++mf)
            #pragma unroll
            for (int nf = 0; nf < 4; ++nf) {
                float4 a4 = *(const float4*)&att_lds[(mf * 16 + wave * 4 + nf) * 16 + lg * 4];
                float o = a4.x * acc[mf][nf][0];
                o = fmaf(a4.y, acc[mf][nf][1], o);
                o = fmaf(a4.z, acc[mf][nf][2], o);
                o = fmaf(a4.w, acc[mf][nf][3], o);
                o += __shfl_xor(o, 16);
                o += __shfl_xor(o, 32);
                o += bvv[nf];
                if (lane < 16)
                    ctx[(size_t)(qbase + mf) * 256 + (wave * 4 + nf) * 16 + lane] = f2b(o);
            }
    }
}

// ---------------- host launcher (r15-proven tail structure) ----------------
extern "C" void kernel_launch(void* const* d_in, const int* in_sizes, int n_in,
                              void* d_out, int out_size, void* d_ws, size_t ws_size,
                              hipStream_t stream)
{
    const float* q_pts   = (const float*)d_in[0];
    const float* s_pts   = (const float*)d_in[1];
    const float* src_f   = (const float*)d_in[2];
    const float* query_f = (const float*)d_in[3];
    const float* W_proj  = (const float*)d_in[4];
    const float* b_proj  = (const float*)d_in[5];
    const float* W_pos   = (const float*)d_in[6];
    const float* b_pos   = (const float*)d_in[7];
    const float* ln1_g   = (const float*)d_in[8];
    const float* ln1_b   = (const float*)d_in[9];
    const float* sa_Wv   = (const float*)d_in[10];
    const float* sa_bv   = (const float*)d_in[11];
    const float* sa_Wo   = (const float*)d_in[12];
    const float* sa_bo   = (const float*)d_in[13];
    const float* ln2_g   = (const float*)d_in[14];
    const float* ln2_b   = (const float*)d_in[15];
    const float* ca_Wq   = (const float*)d_in[16];
    const float* ca_bq   = (const float*)d_in[17];
    const float* ca_Wk   = (const float*)d_in[18];
    /* ca_bk = d_in[19] unused: softmax shift-invariant */
    const float* ca_Wv   = (const float*)d_in[20];
    const float* ca_bv   = (const float*)d_in[21];
    const float* ca_Wo   = (const float*)d_in[22];
    const float* ca_bo   = (const float*)d_in[23];
    const float* ln3_g   = (const float*)d_in[24];
    const float* ln3_b   = (const float*)d_in[25];
    const float* W1      = (const float*)d_in[26];
    const float* b1      = (const float*)d_in[27];
    const float* W2      = (const float*)d_in[28];
    const float* b2      = (const float*)d_in[29];
    const int*   inds    = (const int*)d_in[30];

    char* ws = (char*)d_ws;
    size_t off = 0;
    auto alloc = [&](size_t bytes) { char* p = ws + off; off += (bytes + 1023) & ~(size_t)1023; return p; };

    unsigned short* wTproj = (unsigned short*)alloc(256 * 128 * 2);
    unsigned short* wTcaWq = (unsigned short*)alloc(256 * 256 * 2);
    unsigned short* wTkv   = (unsigned short*)alloc(512 * 256 * 2);
    unsigned short* wTcaWo = (unsigned short*)alloc(256 * 256 * 2);
    unsigned short* wTW1   = (unsigned short*)alloc(256 * 256 * 2);
    unsigned short* wTW2   = (unsigned short*)alloc(256 * 256 * 2);
    unsigned short* wTsa   = (unsigned short*)alloc(256 * 256 * 2);
    float*          bsa    = (float*)alloc(256 * 4);
    float*          penc0  = (float*)alloc(256 * 4);
    float*          bp2    = (float*)alloc(256 * 4);
    unsigned short* srcb   = (unsigned short*)alloc((size_t)NROW_S * 128 * 2);
    unsigned short* qfb    = (unsigned short*)alloc((size_t)NROW_Q * 128 * 2);
    unsigned short* srcp   = (unsigned short*)alloc((size_t)NROW_S * 256 * 2);
    float*          qx     = (float*)alloc((size_t)NROW_Q * 256 * 4);
    unsigned short* hbuf   = (unsigned short*)alloc((size_t)NROW_Q * 256 * 2);
    unsigned short* tbuf   = (unsigned short*)alloc((size_t)NROW_Q * 256 * 2);
    float*          xbuf   = (float*)alloc((size_t)NROW_Q * 256 * 4);
    unsigned short* qbuf   = (unsigned short*)alloc((size_t)NROW_Q * 256 * 2);
    unsigned short* ctxbuf = (unsigned short*)alloc((size_t)NROW_Q * 256 * 2);
    float*          x2buf  = (float*)alloc((size_t)NROW_Q * 256 * 4);

    dim3 bl16(16, 16);
    k_prep<<<dim3(16, 16, 10), bl16, 0, stream>>>(
        W_proj, sa_Wv, sa_Wo, ca_Wq, ca_Wk, ca_Wv, ca_Wo, W1, W2, b_pos,
        wTproj, wTcaWq, wTkv, wTcaWo, wTW1, wTW2, penc0, bp2);
    k_wfuse<<<256, 256, 0, stream>>>(sa_Wv, sa_Wo, sa_bv, sa_bo, wTsa, bsa);

    k_cvt<<<1024, 256, 0, stream>>>(src_f, srcb, NROW_S * 128 / 4);
    k_cvt<<<1024, 256, 0, stream>>>(query_f, qfb, NROW_Q * 128 / 4);

    // src_p = src @ W_proj + b_proj  (bf16)
    k_gemm<0><<<dim3(512, 4), 256, 0, stream>>>(srcb, wTproj, b_proj, nullptr, srcp, NROW_S, 256, 128);
    // query_x = query @ W_proj + b_proj + pos_enc(0); qx f32 + hbuf = LN1(qx)
    k_gemm_ln<0><<<256, 256, 0, stream>>>(qfb, wTproj, b_proj, penc0, ln1_g, ln1_b,
                                          qx, hbuf, NROW_Q, 128);

    // self-attention block (seq len 1, linear-linear fused): xbuf = qx + hbuf@Wsa + bsa ; hbuf = LN2(xbuf)
    k_gemm_ln<1><<<256, 256, 0, stream>>>(hbuf, wTsa, bsa, qx, ln2_g, ln2_b,
                                          xbuf, hbuf, NROW_Q, 256);

    // cross-attention: qbuf = hbuf@caWq+bq ; attn ; x2buf = xbuf + ctx@caWo+bo ; hbuf = LN3
    k_gemm<0><<<dim3(128, 4), 256, 0, stream>>>(hbuf, wTcaWq, ca_bq, nullptr, qbuf, NROW_Q, 256, 256);
    k_attn<<<4096, 256, 0, stream>>>(srcp, qbuf, inds, s_pts, q_pts, W_pos, bp2, wTkv, ca_bv, ctxbuf);
    k_gemm_ln<1><<<256, 256, 0, stream>>>(ctxbuf, wTcaWo, ca_bo, xbuf, ln3_g, ln3_b,
                                          x2buf, hbuf, NROW_Q, 256);

    // feed-forward + nan_to_num -> d_out (f32)
    k_gemm<1><<<dim3(128, 4), 256, 0, stream>>>(hbuf, wTW1, b1, nullptr, tbuf, NROW_Q, 256, 256);
    k_gemm<4><<<dim3(128, 4), 256, 0, stream>>>(tbuf, wTW2, b2, x2buf, d_out, NROW_Q, 256, 256);

    (void)in_sizes; (void)n_in; (void)out_size; (void)ws_size;
}

// Round 18
// 343.428 us; speedup vs baseline: 1.2689x; 1.2235x over previous
//
#include <hip/hip_runtime.h>
#include <hip/hip_bf16.h>
#include <math.h>
#include <stdint.h>

// ---------------- types & helpers ----------------
typedef __attribute__((ext_vector_type(8))) short short8;   // 8 x bf16 (MFMA A/B frag)
typedef __attribute__((ext_vector_type(4))) float floatx4;  // MFMA C/D frag

#define DEVI __device__ __forceinline__

DEVI float b2f(unsigned short u) {
    union { unsigned int i; float f; } v; v.i = ((unsigned int)u) << 16; return v.f;
}
DEVI unsigned short f2b(float f) {   // RNE f32 -> bf16
    unsigned int x = __float_as_uint(f);
    unsigned int r = (x + 0x7fffu + ((x >> 16) & 1u)) >> 16;
    return (unsigned short)r;
}

// global -> LDS direct (16B per lane). LDS dest must be wave-uniform base + lane*16.
#define GLD16(gp, lp)                                                            \
    __builtin_amdgcn_global_load_lds(                                            \
        (__attribute__((address_space(1))) unsigned int*)(gp),                   \
        (__attribute__((address_space(3))) unsigned int*)(lp), 16, 0, 0)

static constexpr int NQ = 4096, NS = 16384;
static constexpr int NROW_Q = 4 * NQ;   // 16384 query rows
static constexpr int NROW_S = 4 * NS;   // 65536 source rows
static constexpr float INV2PI = 0.15915494309189535f;

// ---------------- prep: transpose weights to bf16 [N][K], penc0, bp2 ----------------
// wTkv uses the FRAGMENT-MAJOR layout (r15-verified): frag for (tile, kt) at
// ((tile*8 + kt)*64 + lane)*16B -> weight loads in k_attn fully coalesced.
__global__ void k_prep(const float* Wproj, const float* saWv, const float* saWo,
                       const float* caWq, const float* caWk, const float* caWv,
                       const float* caWo, const float* W1, const float* W2,
                       const float* b_pos,
                       unsigned short* wTproj, unsigned short* wTcaWq,
                       unsigned short* wTkv, unsigned short* wTcaWo,
                       unsigned short* wTW1, unsigned short* wTW2, float* penc0, float* bp2)
{
    int z = blockIdx.z;
    if (z == 9) {   // penc0[c] = pos_enc(0): [0,0,0, cos(b_pos)]; bp2 = b_pos/2pi
        if (blockIdx.x == 0 && blockIdx.y == 0) {
            int c = threadIdx.y * 16 + threadIdx.x;
            float v = 0.f;
            if (c >= 3) {
                float rev = b_pos[c - 3] * INV2PI;
                bp2[c - 3] = rev;
                rev -= floorf(rev);
                v = __builtin_amdgcn_cosf(rev);
            }
            penc0[c] = v;
        }
        return;
    }
    if (z == 1 || z == 2) return;            // saWv/saWo handled by k_wfuse
    int n = blockIdx.x * 16 + threadIdx.x;   // output row (orig col)
    int k = blockIdx.y * 16 + threadIdx.y;   // output col (orig row)
    if (z == 4 || z == 5) {                  // caWk / caWv -> fragment-major wTkv
        int tile = (z == 5 ? 16 : 0) + (n >> 4);
        int kt = k >> 5, lg = (k >> 3) & 3, j = k & 7;
        int lane = lg * 16 + (n & 15);
        wTkv[(size_t)(((tile * 8 + kt) * 64 + lane) * 8 + j)] =
            f2b((z == 4 ? caWk : caWv)[(size_t)k * 256 + n]);
        return;
    }
    const float* src; unsigned short* dst; int K = 256;
    switch (z) {
        case 0: src = Wproj; dst = wTproj; K = 128; break;
        case 3: src = caWq;  dst = wTcaWq; break;
        case 6: src = caWo;  dst = wTcaWo; break;
        case 7: src = W1;    dst = wTW1;   break;
        default: src = W2;   dst = wTW2;   break;
    }
    if (k < K) dst[(size_t)n * K + k] = f2b(src[(size_t)k * 256 + n]);
    (void)saWv; (void)saWo;
}

// fuse self-attn (linear-linear): Wsa = saWv @ saWo (bf16 [n][k]), bsa = bv@Wo + bo
// k = blockIdx (Wv row, scalar-broadcast loads), n = threadIdx (coalesced Wo reads)
__global__ void k_wfuse(const float* Wv, const float* Wo, const float* bv, const float* bo,
                        unsigned short* wTsa, float* bsa)
{
    int k = blockIdx.x, n = threadIdx.x;
    float s = 0.f;
    for (int c = 0; c < 256; ++c) s = fmaf(Wv[k * 256 + c], Wo[c * 256 + n], s);
    wTsa[n * 256 + k] = f2b(s);
    if (k == 0) {
        float s2 = bo[n];
        for (int c = 0; c < 256; ++c) s2 = fmaf(bv[c], Wo[c * 256 + n], s2);
        bsa[n] = s2;
    }
}

// ---------------- f32 -> bf16 convert ----------------
__global__ void k_cvt(const float* in, unsigned short* out, int n4)
{
    int i = blockIdx.x * blockDim.x + threadIdx.x;
    int stride = gridDim.x * blockDim.x;
    for (; i < n4; i += stride) {
        float4 v = ((const float4*)in)[i];
        unsigned long long p =
              (unsigned long long)f2b(v.x)
            | ((unsigned long long)f2b(v.y) << 16)
            | ((unsigned long long)f2b(v.z) << 32)
            | ((unsigned long long)f2b(v.w) << 48);
        ((unsigned long long*)out)[i] = p;
    }
}

// ---------------- MFMA GEMM: out[M][N] = A[M][K](bf16) @ BT[N][K]^T + epilogue ----------------
// EPI: 0 = bf16 out, +bias   1 = bf16 out, +bias, relu   4 = f32 out, +bias+extra, nan_to_num
template<int EPI>
__global__ __launch_bounds__(256, 2)
void k_gemm(const unsigned short* A, const unsigned short* BT, const float* bias,
            const float* extra, void* outp, int M, int N, int K)
{
    __shared__ alignas(16) unsigned short lA[128 * 64];  // [128 rows][64 k], swizzled
    __shared__ alignas(16) unsigned short lB[64 * 64];   // [64 rows][64 k], swizzled
    const int tid = threadIdx.x;
    const int wave = tid >> 6, lane = tid & 63;
    const int m0 = blockIdx.x * 128, n0 = blockIdx.y * 64;
    const int wm = (wave >> 1) * 64, wn = (wave & 1) * 32;
    floatx4 acc[4][2] = {};

    for (int kt = 0; kt < K; kt += 64) {
        __syncthreads();
        #pragma unroll
        for (int c = 0; c < 4; ++c) {   // stage A tile 16KB
            int o = (tid + c * 256) * 16;
            int row = o >> 7, inner = o & 127;
            int srk = inner ^ ((row & 7) << 4);
            GLD16((const char*)A + ((size_t)(m0 + row) * K + kt) * 2 + srk, (char*)lA + o);
        }
        #pragma unroll
        for (int c = 0; c < 2; ++c) {   // stage B tile 8KB
            int o = (tid + c * 256) * 16;
            int row = o >> 7, inner = o & 127;
            int srk = inner ^ ((row & 7) << 4);
            GLD16((const char*)BT + ((size_t)(n0 + row) * K + kt) * 2 + srk, (char*)lB + o);
        }
        __syncthreads();
        #pragma unroll
        for (int kc = 0; kc < 2; ++kc) {
            const int kb = kc * 64 + ((lane >> 4) << 4);
            short8 bf[2];
            #pragma unroll
            for (int nf = 0; nf < 2; ++nf) {
                int nn = wn + nf * 16 + (lane & 15);
                bf[nf] = *(const short8*)((const char*)lB + nn * 128 + (kb ^ ((nn & 7) << 4)));
            }
            #pragma unroll
            for (int mf = 0; mf < 4; ++mf) {
                int rr = wm + mf * 16 + (lane & 15);
                short8 af = *(const short8*)((const char*)lA + rr * 128 + (kb ^ ((rr & 7) << 4)));
                acc[mf][0] = __builtin_amdgcn_mfma_f32_16x16x32_bf16(af, bf[0], acc[mf][0], 0, 0, 0);
                acc[mf][1] = __builtin_amdgcn_mfma_f32_16x16x32_bf16(af, bf[1], acc[mf][1], 0, 0, 0);
            }
        }
    }
    #pragma unroll
    for (int mf = 0; mf < 4; ++mf)
        #pragma unroll
        for (int nf = 0; nf < 2; ++nf)
            #pragma unroll
            for (int r = 0; r < 4; ++r) {
                int row = m0 + wm + mf * 16 + ((lane >> 4) << 2) + r;
                int col = n0 + wn + nf * 16 + (lane & 15);
                float v = acc[mf][nf][r] + bias[col];
                if (EPI == 4) v += extra[(size_t)row * N + col];
                if (EPI == 1) v = fmaxf(v, 0.f);
                if (EPI == 4) {
                    if (isnan(v)) v = 0.f;
                    else if (isinf(v)) v = v > 0.f ? 3.402823466e38f : -3.402823466e38f;
                }
                if (EPI == 0 || EPI == 1)
                    ((unsigned short*)outp)[(size_t)row * N + col] = f2b(v);
                else
                    ((float*)outp)[(size_t)row * N + col] = v;
            }
}

// ---------------- fused GEMM + row-LayerNorm epilogue (r15-proven) ----------------
template<int EPI2>
__global__ __launch_bounds__(256, 2)
void k_gemm_ln(const unsigned short* A, const unsigned short* BT, const float* bias,
               const float* extra, const float* lng, const float* lnb,
               float* outf, unsigned short* outb, int M, int K)
{
    __shared__ alignas(16) unsigned short lA[64 * 64];    // 8 KB
    __shared__ alignas(16) unsigned short lB[256 * 64];   // 32 KB
    const int tid = threadIdx.x, wave = tid >> 6, lane = tid & 63;
    const int l15 = lane & 15, lg = lane >> 4;
    const int m0 = blockIdx.x * 64;
    floatx4 acc[16] = {};

    for (int kt = 0; kt < K; kt += 64) {
        __syncthreads();
        #pragma unroll
        for (int c = 0; c < 2; ++c) {   // stage A 8KB
            int o = (tid + c * 256) * 16;
            int row = o >> 7, inner = o & 127;
            int srk = inner ^ ((row & 7) << 4);
            GLD16((const char*)A + ((size_t)(m0 + row) * K + kt) * 2 + srk, (char*)lA + o);
        }
        #pragma unroll
        for (int c = 0; c < 8; ++c) {   // stage B 32KB (all 256 n-rows)
            int o = (tid + c * 256) * 16;
            int row = o >> 7, inner = o & 127;
            int srk = inner ^ ((row & 7) << 4);
            GLD16((const char*)BT + ((size_t)row * K + kt) * 2 + srk, (char*)lB + o);
        }
        __syncthreads();
        #pragma unroll
        for (int kc = 0; kc < 2; ++kc) {
            const int kb = kc * 64 + (lg << 4);
            int rr = wave * 16 + l15;
            short8 af = *(const short8*)((const char*)lA + rr * 128 + (kb ^ ((rr & 7) << 4)));
            #pragma unroll
            for (int nf = 0; nf < 16; ++nf) {
                int nn = nf * 16 + l15;
                short8 bf = *(const short8*)((const char*)lB + nn * 128 + (kb ^ ((nn & 7) << 4)));
                acc[nf] = __builtin_amdgcn_mfma_f32_16x16x32_bf16(af, bf, acc[nf], 0, 0, 0);
            }
        }
    }

    #pragma unroll
    for (int nf = 0; nf < 16; ++nf) {
        int col = nf * 16 + l15;
        float bi = bias[col] + (EPI2 == 0 ? extra[col] : 0.f);
        #pragma unroll
        for (int r = 0; r < 4; ++r) {
            int row = m0 + wave * 16 + lg * 4 + r;
            float v = acc[nf][r] + bi;
            if (EPI2 == 1) v += extra[(size_t)row * 256 + col];
            acc[nf][r] = v;
            outf[(size_t)row * 256 + col] = v;
        }
    }
    float mean[4], inv[4];
    #pragma unroll
    for (int r = 0; r < 4; ++r) {
        float s = 0.f;
        #pragma unroll
        for (int nf = 0; nf < 16; ++nf) s += acc[nf][r];
        #pragma unroll
        for (int t = 1; t <= 8; t <<= 1) s += __shfl_xor(s, t);
        mean[r] = s * (1.f / 256.f);
        float q = 0.f;
        #pragma unroll
        for (int nf = 0; nf < 16; ++nf) { float d = acc[nf][r] - mean[r]; q += d * d; }
        #pragma unroll
        for (int t = 1; t <= 8; t <<= 1) q += __shfl_xor(q, t);
        inv[r] = 1.0f / sqrtf(q * (1.f / 256.f) + 1e-5f);
    }
    #pragma unroll
    for (int nf = 0; nf < 16; ++nf) {
        int col = nf * 16 + l15;
        float g = lng[col], b = lnb[col];
        #pragma unroll
        for (int r = 0; r < 4; ++r) {
            int row = m0 + wave * 16 + lg * 4 + r;
            outb[(size_t)row * 256 + col] = f2b((acc[nf][r] - mean[r]) * inv[r] * g + b);
        }
    }
}

// ---------------- fused neighbor attention (r15: fragment-major weights, 4 blocks/CU) ----
// block = 4 queries (64 neighbor rows), 256 threads (4 waves). Per-thread independent
// gather (proven; coalesced-gather variant regressed due to barrier dependency, r17).
__global__ __launch_bounds__(256, 4)
void k_attn(const unsigned short* srcp, const unsigned short* qb, const int* inds,
            const float* s_pts, const float* q_pts, const float* W_pos, const float* bp2,
            const unsigned short* wTkv, const float* bv, unsigned short* ctx)
{
    __shared__ alignas(16) unsigned short nx[64 * 256];   // 32 KB, XOR-swizzled rows
    __shared__ alignas(16) float att_lds[4 * 16 * 16];    // 4 KB [q][h][k]
    __shared__ alignas(16) unsigned short qls[4 * 256];   // 2 KB raw q (bf16)
    __shared__ alignas(16) float dist_lds[64];            // (dist/RADIUS)^2
    const int tid = threadIdx.x, wave = tid >> 6, lane = tid & 63;
    const int qbase = blockIdx.x * 4;
    const int l15 = lane & 15, lg = lane >> 4;

    if (tid < 128)
        *(uint4*)&qls[tid * 8] = *(const uint4*)(qb + (size_t)qbase * 256 + tid * 8);

    float bvv[4];
    #pragma unroll
    for (int nf = 0; nf < 4; ++nf) bvv[nf] = bv[(wave * 4 + nf) * 16 + l15];

    // ---- P1: gather + positional encoding (per-thread independent) ----
    {
        int r = tid >> 2, sub = tid & 3;
        int qi = qbase + (r >> 4);
        int bb = qi >> 12;
        int k = r & 15;
        int raw = inds[((size_t)qi << 4) + k];
        int idx = raw % (NS + 1); if (idx < 0) idx += NS + 1;
        bool shadow = (idx == NS);
        const int c0 = sub * 64;
        const unsigned short* srow = srcp + ((size_t)bb * NS + (shadow ? 0 : idx)) * 256 + c0;
        short8 sv[8];
        #pragma unroll
        for (int j = 0; j < 8; ++j) sv[j] = *(const short8*)(srow + j * 8);

        float px = q_pts[(size_t)qi * 3], py = q_pts[(size_t)qi * 3 + 1], pz = q_pts[(size_t)qi * 3 + 2];
        float sx, sy, sz;
        if (shadow) { sx = sy = sz = 1e6f; }
        else {
            const float* sp = s_pts + ((size_t)bb * NS + idx) * 3;
            sx = sp[0]; sy = sp[1]; sz = sp[2];
        }
        float tx = (sx - px) * 0.25f, ty = (sy - py) * 0.25f, tz = (sz - pz) * 0.25f;
        if (sub == 0) dist_lds[r] = tx * tx + ty * ty + tz * tz;

        #pragma unroll
        for (int cc = 0; cc < 64; cc += 8) {
            short8 vals;
            #pragma unroll
            for (int j = 0; j < 8; ++j) {
                int c = c0 + cc + j;
                float pe;
                if (c == 0) pe = tx;
                else if (c == 1) pe = ty;
                else if (c == 2) pe = tz;
                else {
                    int jj = c - 3;
                    float rev = fmaf(tx, W_pos[jj],
                                fmaf(ty, W_pos[253 + jj],
                                fmaf(tz, W_pos[506 + jj], bp2[jj])));
                    rev -= floorf(rev);
                    pe = __builtin_amdgcn_cosf(rev);
                }
                float sval = shadow ? 0.f : b2f((unsigned short)sv[cc / 8][j]);
                vals[j] = (short)f2b(sval + pe);
            }
            int byte = (c0 + cc) * 2;
            *(short8*)((char*)nx + r * 512 + (byte ^ ((r & 7) << 4))) = vals;
        }
    }
    __syncthreads();

    floatx4 acc[4][4];

    // ---- P2: kk = nx @ Wk (coalesced fragment-major weight loads) ----
    #pragma unroll
    for (int mf = 0; mf < 4; ++mf)
        #pragma unroll
        for (int nf = 0; nf < 4; ++nf) acc[mf][nf] = floatx4{0.f, 0.f, 0.f, 0.f};

    #pragma unroll 2
    for (int kt = 0; kt < 8; ++kt) {
        const int kb = kt * 64 + (lg << 4);
        short8 bfr[4];
        #pragma unroll
        for (int nf = 0; nf < 4; ++nf) {
            int tile = wave * 4 + nf;
            bfr[nf] = *(const short8*)((const char*)wTkv + (size_t)(((tile * 8 + kt) * 64 + lane) << 4));
        }
        #pragma unroll
        for (int mf = 0; mf < 4; ++mf) {
            int rr = mf * 16 + l15;
            short8 af = *(const short8*)((const char*)nx + rr * 512 + (kb ^ ((rr & 7) << 4)));
            #pragma unroll
            for (int nf = 0; nf < 4; ++nf)
                acc[mf][nf] = __builtin_amdgcn_mfma_f32_16x16x32_bf16(af, bfr[nf], acc[mf][nf], 0, 0, 0);
        }
    }

    // ---- P3: scores + softmax (in-register; qv from LDS) ----
    {
        #pragma unroll
        for (int mf = 0; mf < 4; ++mf) {
            float4 d4 = *(const float4*)&dist_lds[mf * 16 + lg * 4];
            float dd4[4] = {d4.x, d4.y, d4.z, d4.w};
            #pragma unroll
            for (int nf = 0; nf < 4; ++nf) {
                float qvv = b2f(qls[mf * 256 + (wave * 4 + nf) * 16 + l15]);
                float s[4];
                #pragma unroll
                for (int rr = 0; rr < 4; ++rr) s[rr] = acc[mf][nf][rr] * qvv;
                #pragma unroll
                for (int t = 1; t <= 8; t <<= 1)
                    #pragma unroll
                    for (int rr = 0; rr < 4; ++rr) s[rr] += __shfl_xor(s[rr], t);
                #pragma unroll
                for (int rr = 0; rr < 4; ++rr)
                    s[rr] = (dd4[rr] > 1.0f) ? -1e9f : s[rr] * 0.25f;
                float m = fmaxf(fmaxf(s[0], s[1]), fmaxf(s[2], s[3]));
                m = fmaxf(m, __shfl_xor(m, 16));
                m = fmaxf(m, __shfl_xor(m, 32));
                float p[4], su = 0.f;
                #pragma unroll
                for (int rr = 0; rr < 4; ++rr) { p[rr] = __expf(s[rr] - m); su += p[rr]; }
                su += __shfl_xor(su, 16);
                su += __shfl_xor(su, 32);
                float iv = __builtin_amdgcn_rcpf(su);
                if (l15 == 0) {
                    float4 a4 = {p[0] * iv, p[1] * iv, p[2] * iv, p[3] * iv};
                    *(float4*)&att_lds[(mf * 16 + wave * 4 + nf) * 16 + lg * 4] = a4;
                }
            }
        }
    }

    // ---- P4: vv = nx @ Wv, ctx = att . vv ----
    #pragma unroll
    for (int mf = 0; mf < 4; ++mf)
        #pragma unroll
        for (int nf = 0; nf < 4; ++nf) acc[mf][nf] = floatx4{0.f, 0.f, 0.f, 0.f};

    #pragma unroll 2
    for (int kt = 0; kt < 8; ++kt) {
        const int kb = kt * 64 + (lg << 4);
        short8 bfr[4];
        #pragma unroll
        for (int nf = 0; nf < 4; ++nf) {
            int tile = 16 + wave * 4 + nf;
            bfr[nf] = *(const short8*)((const char*)wTkv + (size_t)(((tile * 8 + kt) * 64 + lane) << 4));
        }
        #pragma unroll
        for (int mf = 0; mf < 4; ++mf) {
            int rr = mf * 16 + l15;
            short8 af = *(const short8*)((const char*)nx + rr * 512 + (kb ^ ((rr & 7) << 4)));
            #pragma unroll
            for (int nf = 0; nf < 4; ++nf)
                acc[mf][nf] = __builtin_amdgcn_mfma_f32_16x16x32_bf16(af, bfr[nf], acc[mf][nf], 0, 0, 0);
        }
    }

    {
        #pragma unroll
        for (int mf = 0; mf < 4; ++mf)
            #pragma unroll
            for (int nf = 0; nf < 4; ++nf) {
                float4 a4 = *(const float4*)&att_lds[(mf * 16 + wave * 4 + nf) * 16 + lg * 4];
                float o = a4.x * acc[mf][nf][0];
                o = fmaf(a4.y, acc[mf][nf][1], o);
                o = fmaf(a4.z, acc[mf][nf][2], o);
                o = fmaf(a4.w, acc[mf][nf][3], o);
                o += __shfl_xor(o, 16);
                o += __shfl_xor(o, 32);
                o += bvv[nf];
                if (lane < 16)
                    ctx[(size_t)(qbase + mf) * 256 + (wave * 4 + nf) * 16 + lane] = f2b(o);
            }
    }
}

// ---------------- host launcher (r15-proven structure) ----------------
extern "C" void kernel_launch(void* const* d_in, const int* in_sizes, int n_in,
                              void* d_out, int out_size, void* d_ws, size_t ws_size,
                              hipStream_t stream)
{
    const float* q_pts   = (const float*)d_in[0];
    const float* s_pts   = (const float*)d_in[1];
    const float* src_f   = (const float*)d_in[2];
    const float* query_f = (const float*)d_in[3];
    const float* W_proj  = (const float*)d_in[4];
    const float* b_proj  = (const float*)d_in[5];
    const float* W_pos   = (const float*)d_in[6];
    const float* b_pos   = (const float*)d_in[7];
    const float* ln1_g   = (const float*)d_in[8];
    const float* ln1_b   = (const float*)d_in[9];
    const float* sa_Wv   = (const float*)d_in[10];
    const float* sa_bv   = (const float*)d_in[11];
    const float* sa_Wo   = (const float*)d_in[12];
    const float* sa_bo   = (const float*)d_in[13];
    const float* ln2_g   = (const float*)d_in[14];
    const float* ln2_b   = (const float*)d_in[15];
    const float* ca_Wq   = (const float*)d_in[16];
    const float* ca_bq   = (const float*)d_in[17];
    const float* ca_Wk   = (const float*)d_in[18];
    /* ca_bk = d_in[19] unused: softmax shift-invariant */
    const float* ca_Wv   = (const float*)d_in[20];
    const float* ca_bv   = (const float*)d_in[21];
    const float* ca_Wo   = (const float*)d_in[22];
    const float* ca_bo   = (const float*)d_in[23];
    const float* ln3_g   = (const float*)d_in[24];
    const float* ln3_b   = (const float*)d_in[25];
    const float* W1      = (const float*)d_in[26];
    const float* b1      = (const float*)d_in[27];
    const float* W2      = (const float*)d_in[28];
    const float* b2      = (const float*)d_in[29];
    const int*   inds    = (const int*)d_in[30];

    char* ws = (char*)d_ws;
    size_t off = 0;
    auto alloc = [&](size_t bytes) { char* p = ws + off; off += (bytes + 1023) & ~(size_t)1023; return p; };

    unsigned short* wTproj = (unsigned short*)alloc(256 * 128 * 2);
    unsigned short* wTcaWq = (unsigned short*)alloc(256 * 256 * 2);
    unsigned short* wTkv   = (unsigned short*)alloc(512 * 256 * 2);
    unsigned short* wTcaWo = (unsigned short*)alloc(256 * 256 * 2);
    unsigned short* wTW1   = (unsigned short*)alloc(256 * 256 * 2);
    unsigned short* wTW2   = (unsigned short*)alloc(256 * 256 * 2);
    unsigned short* wTsa   = (unsigned short*)alloc(256 * 256 * 2);
    float*          bsa    = (float*)alloc(256 * 4);
    float*          penc0  = (float*)alloc(256 * 4);
    float*          bp2    = (float*)alloc(256 * 4);
    unsigned short* srcb   = (unsigned short*)alloc((size_t)NROW_S * 128 * 2);
    unsigned short* qfb    = (unsigned short*)alloc((size_t)NROW_Q * 128 * 2);
    unsigned short* srcp   = (unsigned short*)alloc((size_t)NROW_S * 256 * 2);
    float*          qx     = (float*)alloc((size_t)NROW_Q * 256 * 4);
    unsigned short* hbuf   = (unsigned short*)alloc((size_t)NROW_Q * 256 * 2);
    unsigned short* tbuf   = (unsigned short*)alloc((size_t)NROW_Q * 256 * 2);
    float*          xbuf   = (float*)alloc((size_t)NROW_Q * 256 * 4);
    unsigned short* qbuf   = (unsigned short*)alloc((size_t)NROW_Q * 256 * 2);
    unsigned short* ctxbuf = (unsigned short*)alloc((size_t)NROW_Q * 256 * 2);
    float*          x2buf  = (float*)alloc((size_t)NROW_Q * 256 * 4);

    dim3 bl16(16, 16);
    k_prep<<<dim3(16, 16, 10), bl16, 0, stream>>>(
        W_proj, sa_Wv, sa_Wo, ca_Wq, ca_Wk, ca_Wv, ca_Wo, W1, W2, b_pos,
        wTproj, wTcaWq, wTkv, wTcaWo, wTW1, wTW2, penc0, bp2);
    k_wfuse<<<256, 256, 0, stream>>>(sa_Wv, sa_Wo, sa_bv, sa_bo, wTsa, bsa);

    k_cvt<<<1024, 256, 0, stream>>>(src_f, srcb, NROW_S * 128 / 4);
    k_cvt<<<1024, 256, 0, stream>>>(query_f, qfb, NROW_Q * 128 / 4);

    // src_p = src @ W_proj + b_proj  (bf16)
    k_gemm<0><<<dim3(512, 4), 256, 0, stream>>>(srcb, wTproj, b_proj, nullptr, srcp, NROW_S, 256, 128);
    // query_x = query @ W_proj + b_proj + pos_enc(0); qx f32 + hbuf = LN1(qx)
    k_gemm_ln<0><<<256, 256, 0, stream>>>(qfb, wTproj, b_proj, penc0, ln1_g, ln1_b,
                                          qx, hbuf, NROW_Q, 128);

    // self-attention block (seq len 1, linear-linear fused): xbuf = qx + hbuf@Wsa + bsa ; hbuf = LN2(xbuf)
    k_gemm_ln<1><<<256, 256, 0, stream>>>(hbuf, wTsa, bsa, qx, ln2_g, ln2_b,
                                          xbuf, hbuf, NROW_Q, 256);

    // cross-attention: qbuf = hbuf@caWq+bq ; attn ; x2buf = xbuf + ctx@caWo+bo ; hbuf = LN3
    k_gemm<0><<<dim3(128, 4), 256, 0, stream>>>(hbuf, wTcaWq, ca_bq, nullptr, qbuf, NROW_Q, 256, 256);
    k_attn<<<4096, 256, 0, stream>>>(srcp, qbuf, inds, s_pts, q_pts, W_pos, bp2, wTkv, ca_bv, ctxbuf);
    k_gemm_ln<1><<<256, 256, 0, stream>>>(ctxbuf, wTcaWo, ca_bo, xbuf, ln3_g, ln3_b,
                                          x2buf, hbuf, NROW_Q, 256);

    // feed-forward + nan_to_num -> d_out (f32)
    k_gemm<1><<<dim3(128, 4), 256, 0, stream>>>(hbuf, wTW1, b1, nullptr, tbuf, NROW_Q, 256, 256);
    k_gemm<4><<<dim3(128, 4), 256, 0, stream>>>(tbuf, wTW2, b2, x2buf, d_out, NROW_Q, 256, 256);

    (void)in_sizes; (void)n_in; (void)out_size; (void)ws_size;
}